// Round 2
// baseline (15120.186 us; speedup 1.0000x reference)
//
#include <hip/hip_runtime.h>
#include <hip/hip_cooperative_groups.h>
#include <math.h>

namespace cg = cooperative_groups;

#define NB 256
#define NT 1024
#define NW 16      // waves per block
#define TT 100
#define MM 10
#define NN 10
#define HID 2000
#define H1 1600
#define H2 400
#define G3 6000    // 3*HID

__device__ __forceinline__ float sigf(float x) { return 1.f / (1.f + __expf(-x)); }
__device__ __forceinline__ float tanhfast(float x) { return 2.f / (1.f + __expf(-2.f * x)) - 1.f; }

// one row dot-product per wave; x in LDS; K compile-time so ALL weight loads
// are issued back-to-back (8x MLP per wave) before the FMA chain.
template<int K>
__device__ __forceinline__ float rowdotT(const float* __restrict__ row,
                                         const float* __restrict__ x, int ln) {
  constexpr int NFULL = K / 256;            // float4 rounds all 64 lanes do
  constexpr int REM   = K - NFULL * 256;    // leftover elements (lane-partial)
  const int base = ln * 4;
  float4 w[NFULL + (REM ? 1 : 0)];
  #pragma unroll
  for (int i = 0; i < NFULL; ++i)
    w[i] = *reinterpret_cast<const float4*>(row + base + i * 256);
  bool tail = false;
  if constexpr (REM != 0) {
    tail = (base + NFULL * 256 + 3 < K);
    if (tail) w[NFULL] = *reinterpret_cast<const float4*>(row + base + NFULL * 256);
  }
  float acc = 0.f;
  #pragma unroll
  for (int i = 0; i < NFULL; ++i) {
    const float4 xv = *reinterpret_cast<const float4*>(x + base + i * 256);
    acc = fmaf(w[i].x, xv.x, acc);
    acc = fmaf(w[i].y, xv.y, acc);
    acc = fmaf(w[i].z, xv.z, acc);
    acc = fmaf(w[i].w, xv.w, acc);
  }
  if constexpr (REM != 0) {
    if (tail) {
      const float4 xv = *reinterpret_cast<const float4*>(x + base + NFULL * 256);
      acc = fmaf(w[NFULL].x, xv.x, acc);
      acc = fmaf(w[NFULL].y, xv.y, acc);
      acc = fmaf(w[NFULL].z, xv.z, acc);
      acc = fmaf(w[NFULL].w, xv.w, acc);
    }
  }
  #pragma unroll
  for (int off = 32; off; off >>= 1) acc += __shfl_xor(acc, off, 64);
  return acc;
}

__global__ __launch_bounds__(NT)
void knet_kernel(const float* __restrict__ y, const float* __restrict__ m1x0,
                 const float* __restrict__ F, const float* __restrict__ Hm,
                 const float* __restrict__ h0,
                 const float* __restrict__ W1, const float* __restrict__ b1,
                 const float* __restrict__ Wi0, const float* __restrict__ Wh0,
                 const float* __restrict__ bi0, const float* __restrict__ bh0,
                 const float* __restrict__ Wi1, const float* __restrict__ Wh1,
                 const float* __restrict__ bi1, const float* __restrict__ bh1,
                 const float* __restrict__ W2, const float* __restrict__ b2,
                 const float* __restrict__ W3, const float* __restrict__ b3,
                 float* __restrict__ out, float* __restrict__ ws)
{
  cg::grid_group grid = cg::this_grid();
  const int blk = blockIdx.x, tid = threadIdx.x;
  const int wv = tid >> 6, ln = tid & 63;

  float* a_ws   = ws;            // 1600
  float* gi0_ws = ws + 1600;     // 6000
  float* gh0_ws = ws + 7600;     // 6000
  float* gi1_ws = ws + 13600;    // 6000
  float* gh1_ws = ws + 19600;    // 6000
  float* g_ws   = ws + 25600;    // 400
  float* h1b    = ws + 26000;    // 2*2000 ping-pong
  float* h2b    = ws + 30000;    // 2*2000 ping-pong

  __shared__ __align__(16) float xs[2048];
  __shared__ float post_s[MM], prevpost_s[MM], prevprior_s[MM], prior_s[MM];
  __shared__ float dy_s[NN], yprev_s[NN], tmp_s[MM];
  __shared__ float d1_s[NN], d3_s[MM], d4_s[MM];
  __shared__ float kin_s[32], nrm_s[3];
  __shared__ float v_s[MM * NN], np_s[MM];

  for (int t = 0; t < TT; ++t) {
    // ---------------- Phase AE ----------------
    if (blk == NB - 1) {
      if (t > 0) {
        // finalize step t-1: v = W3@g + b3, new_post = prior + KG@dy
        for (int j = tid; j < H2; j += NT) xs[j] = g_ws[j];
        __syncthreads();
        for (int r = wv; r < MM * NN; r += NW) {
          float acc = rowdotT<H2>(W3 + (size_t)r * H2, xs, ln);
          if (ln == 0) v_s[r] = acc + b3[r];
        }
        __syncthreads();
        if (tid < MM) {
          float np = prior_s[tid];
          #pragma unroll
          for (int j = 0; j < NN; ++j) np = fmaf(v_s[tid * NN + j], dy_s[j], np);
          out[tid * TT + (t - 1)] = np;
          np_s[tid] = np;
        }
        __syncthreads();
        if (tid < MM) {
          prevpost_s[tid]  = post_s[tid];
          prevprior_s[tid] = prior_s[tid];
          post_s[tid]      = np_s[tid];
        }
        __syncthreads();
      } else {
        // init carry in LDS
        if (tid < MM) {
          post_s[tid]      = m1x0[tid];
          prevpost_s[tid]  = 0.f;
          prevprior_s[tid] = m1x0[tid];
          float tv = 0.f;
          for (int j = 0; j < MM; ++j) tv = fmaf(F[tid * MM + j], m1x0[j], tv);
          tmp_s[tid] = tv;
        }
        __syncthreads();
        if (tid < NN) {
          float yp = 0.f;
          for (int j = 0; j < MM; ++j) yp = fmaf(Hm[tid * MM + j], tmp_s[j], yp);
          yprev_s[tid] = yp;
        }
        __syncthreads();
      }
      // features for step t
      if (tid < MM) {
        float pr = 0.f;
        for (int j = 0; j < MM; ++j) pr = fmaf(F[tid * MM + j], post_s[j], pr);
        prior_s[tid] = pr;
      }
      __syncthreads();
      if (tid < NN) {
        float my = 0.f;
        for (int j = 0; j < MM; ++j) my = fmaf(Hm[tid * MM + j], prior_s[j], my);
        float yt = y[tid * TT + t];
        dy_s[tid] = yt - my;
        d1_s[tid] = yt - ((t == 0) ? yprev_s[tid] : y[tid * TT + (t - 1)]);
        d3_s[tid] = post_s[tid] - prevpost_s[tid];
        d4_s[tid] = post_s[tid] - prevprior_s[tid];
      }
      __syncthreads();
      if (tid == 0) {
        float n1 = 0.f, n3 = 0.f, n4 = 0.f;
        for (int j = 0; j < NN; ++j) n1 += d1_s[j] * d1_s[j];
        for (int j = 0; j < MM; ++j) { n3 += d3_s[j] * d3_s[j]; n4 += d4_s[j] * d4_s[j]; }
        nrm_s[0] = fmaxf(sqrtf(n1), 1e-12f);
        nrm_s[1] = fmaxf(sqrtf(n3), 1e-12f);
        nrm_s[2] = fmaxf(sqrtf(n4), 1e-12f);
      }
      __syncthreads();
      if (tid < NN) kin_s[tid] = d1_s[tid] / nrm_s[0];
      if (tid < MM) {
        kin_s[NN + tid]      = d3_s[tid] / nrm_s[1];
        kin_s[NN + MM + tid] = d4_s[tid] / nrm_s[2];
      }
      __syncthreads();
      // a = relu(W1 @ kin + b1): thread-per-row, K=30 (unrolled -> 30 loads in flight)
      for (int r = tid; r < H1; r += NT) {
        float acc = b1[r];
        const float* row = W1 + (size_t)r * 30;
        #pragma unroll
        for (int k = 0; k < 30; ++k) acc = fmaf(row[k], kin_s[k], acc);
        a_ws[r] = fmaxf(acc, 0.f);
      }
    } else {
      // gh0 = Wh0@h1 + bh0  (blocks 0..126) ; gh1 = Wh1@h2 + bh1 (blocks 127..254)
      const float* h1cur = (t == 0) ? h0 : (h1b + ((t - 1) & 1) * HID);
      const float* h2cur = (t == 0) ? (h0 + HID) : (h2b + ((t - 1) & 1) * HID);
      const bool grp0 = (blk < 127);
      const float* xsrc = grp0 ? h1cur : h2cur;
      for (int j = tid; j < HID; j += NT) xs[j] = xsrc[j];
      __syncthreads();
      if (grp0) {
        const int gw = blk * NW + wv;              // 0..2031
        for (int r = gw; r < G3; r += 127 * NW) {
          float acc = rowdotT<HID>(Wh0 + (size_t)r * HID, xs, ln);
          if (ln == 0) gh0_ws[r] = acc + bh0[r];
        }
      } else {
        const int gw = (blk - 127) * NW + wv;      // 0..2047
        for (int r = gw; r < G3; r += 128 * NW) {
          float acc = rowdotT<HID>(Wh1 + (size_t)r * HID, xs, ln);
          if (ln == 0) gh1_ws[r] = acc + bh1[r];
        }
      }
    }
    grid.sync();

    // ---------------- Phase B: gi0 = Wi0@a + bi0 ----------------
    for (int j = tid; j < H1; j += NT) xs[j] = a_ws[j];
    __syncthreads();
    {
      const int gw = blk * NW + wv;                // 0..4095
      for (int r = gw; r < G3; r += NB * NW) {
        float acc = rowdotT<H1>(Wi0 + (size_t)r * H1, xs, ln);
        if (ln == 0) gi0_ws[r] = acc + bi0[r];
      }
    }
    grid.sync();

    // ---------------- Phase C: h1n (redundant) then gi1 = Wi1@h1n + bi1 ----------------
    {
      const float* h1cur = (t == 0) ? h0 : (h1b + ((t - 1) & 1) * HID);
      for (int j = tid; j < HID; j += NT) {
        float r = sigf(gi0_ws[j] + gh0_ws[j]);
        float z = sigf(gi0_ws[HID + j] + gh0_ws[HID + j]);
        float n = tanhfast(gi0_ws[2 * HID + j] + r * gh0_ws[2 * HID + j]);
        xs[j] = (1.f - z) * n + z * h1cur[j];
      }
      __syncthreads();
      if (blk == 0) {
        float* h1nxt = h1b + (t & 1) * HID;
        for (int j = tid; j < HID; j += NT) h1nxt[j] = xs[j];
      }
      const int gw = blk * NW + wv;
      for (int r = gw; r < G3; r += NB * NW) {
        float acc = rowdotT<HID>(Wi1 + (size_t)r * HID, xs, ln);
        if (ln == 0) gi1_ws[r] = acc + bi1[r];
      }
    }
    grid.sync();

    // ---------------- Phase D: h2n (redundant) then g = relu(W2@h2n + b2) ----------------
    {
      const float* h2cur = (t == 0) ? (h0 + HID) : (h2b + ((t - 1) & 1) * HID);
      if (blk <= 25) {
        for (int j = tid; j < HID; j += NT) {
          float r = sigf(gi1_ws[j] + gh1_ws[j]);
          float z = sigf(gi1_ws[HID + j] + gh1_ws[HID + j]);
          float n = tanhfast(gi1_ws[2 * HID + j] + r * gh1_ws[2 * HID + j]);
          xs[j] = (1.f - z) * n + z * h2cur[j];
        }
      }
      __syncthreads();
      if (blk < 25) {
        const int r = blk * NW + wv;               // 0..399 (one row per wave)
        float acc = rowdotT<HID>(W2 + (size_t)r * HID, xs, ln);
        if (ln == 0) g_ws[r] = fmaxf(acc + b2[r], 0.f);
      } else if (blk == 25) {
        float* h2nxt = h2b + (t & 1) * HID;
        for (int j = tid; j < HID; j += NT) h2nxt[j] = xs[j];
      }
    }
    grid.sync();
  }

  // ---------------- Tail: finalize step T-1 ----------------
  if (blk == NB - 1) {
    for (int j = tid; j < H2; j += NT) xs[j] = g_ws[j];
    __syncthreads();
    for (int r = wv; r < MM * NN; r += NW) {
      float acc = rowdotT<H2>(W3 + (size_t)r * H2, xs, ln);
      if (ln == 0) v_s[r] = acc + b3[r];
    }
    __syncthreads();
    if (tid < MM) {
      float np = prior_s[tid];
      #pragma unroll
      for (int j = 0; j < NN; ++j) np = fmaf(v_s[tid * NN + j], dy_s[j], np);
      out[tid * TT + (TT - 1)] = np;
    }
  }
}

extern "C" void kernel_launch(void* const* d_in, const int* in_sizes, int n_in,
                              void* d_out, int out_size, void* d_ws, size_t ws_size,
                              hipStream_t stream) {
  const float* y    = (const float*)d_in[0];
  const float* m1x0 = (const float*)d_in[1];
  const float* F    = (const float*)d_in[2];
  const float* Hm   = (const float*)d_in[3];
  const float* h0   = (const float*)d_in[4];
  const float* W1   = (const float*)d_in[5];
  const float* b1   = (const float*)d_in[6];
  const float* Wi0  = (const float*)d_in[7];
  const float* Wh0  = (const float*)d_in[8];
  const float* bi0  = (const float*)d_in[9];
  const float* bh0  = (const float*)d_in[10];
  const float* Wi1  = (const float*)d_in[11];
  const float* Wh1  = (const float*)d_in[12];
  const float* bi1  = (const float*)d_in[13];
  const float* bh1  = (const float*)d_in[14];
  const float* W2   = (const float*)d_in[15];
  const float* b2   = (const float*)d_in[16];
  const float* W3   = (const float*)d_in[17];
  const float* b3   = (const float*)d_in[18];
  float* out = (float*)d_out;
  float* ws  = (float*)d_ws;

  void* args[] = { &y, &m1x0, &F, &Hm, &h0, &W1, &b1, &Wi0, &Wh0, &bi0, &bh0,
                   &Wi1, &Wh1, &bi1, &bh1, &W2, &b2, &W3, &b3, &out, &ws };
  hipLaunchCooperativeKernel((const void*)knet_kernel, dim3(NB), dim3(NT),
                             args, 0, stream);
}

// Round 3
// 6117.124 us; speedup vs baseline: 2.4718x; 2.4718x over previous
//
#include <hip/hip_runtime.h>
#include <math.h>

#define NB 256
#define NT 1024
#define NW 16      // waves per block
#define TT 100
#define MM 10
#define NN 10
#define HID 2000
#define H1 1600
#define H2 400
#define G3 6000    // 3*HID

#define SCOPE_AGENT __HIP_MEMORY_SCOPE_AGENT

__device__ __forceinline__ float sigf(float x) { return 1.f / (1.f + __expf(-x)); }
__device__ __forceinline__ float tanhfast(float x) { return 2.f / (1.f + __expf(-2.f * x)) - 1.f; }

// ---- cross-XCD coherent access (bypass non-coherent L2, no fences) ----
__device__ __forceinline__ float ld_coh(const float* p) {
  return __hip_atomic_load(p, __ATOMIC_RELAXED, SCOPE_AGENT);
}
__device__ __forceinline__ void st_coh(float* p, float v) {
  __hip_atomic_store(p, v, __ATOMIC_RELAXED, SCOPE_AGENT);
}
// stage n floats (n even, 8B-aligned src) from coherent global into LDS
__device__ __forceinline__ void stage_coh(const float* __restrict__ src,
                                          float* __restrict__ dst, int n, int tid) {
  const unsigned long long* s = (const unsigned long long*)src;
  const int n2 = n >> 1;
  for (int j = tid; j < n2; j += NT) {
    unsigned long long v = __hip_atomic_load(s + j, __ATOMIC_RELAXED, SCOPE_AGENT);
    union { unsigned long long u; float f[2]; } c; c.u = v;
    dst[2 * j]     = c.f[0];
    dst[2 * j + 1] = c.f[1];
  }
}

// ---- lightweight grid barrier: relaxed atomics, monotone counter ----
__device__ __forceinline__ void gridbar(unsigned* bar, unsigned target, int tid) {
  __syncthreads();   // drains vmcnt(0): all prior coherent stores are complete
  if (tid == 0) {
    __hip_atomic_fetch_add(bar, 1u, __ATOMIC_RELAXED, SCOPE_AGENT);
    while (__hip_atomic_load(bar, __ATOMIC_RELAXED, SCOPE_AGENT) < target) { }
  }
  __syncthreads();
}

// one row dot-product per wave; x in LDS; K compile-time
template<int K>
__device__ __forceinline__ float rowdotT(const float* __restrict__ row,
                                         const float* __restrict__ x, int ln) {
  constexpr int NFULL = K / 256;
  constexpr int REM   = K - NFULL * 256;
  const int base = ln * 4;
  float4 w[NFULL + (REM ? 1 : 0)];
  #pragma unroll
  for (int i = 0; i < NFULL; ++i)
    w[i] = *reinterpret_cast<const float4*>(row + base + i * 256);
  bool tail = false;
  if constexpr (REM != 0) {
    tail = (base + NFULL * 256 + 3 < K);
    if (tail) w[NFULL] = *reinterpret_cast<const float4*>(row + base + NFULL * 256);
  }
  float acc = 0.f;
  #pragma unroll
  for (int i = 0; i < NFULL; ++i) {
    const float4 xv = *reinterpret_cast<const float4*>(x + base + i * 256);
    acc = fmaf(w[i].x, xv.x, acc);
    acc = fmaf(w[i].y, xv.y, acc);
    acc = fmaf(w[i].z, xv.z, acc);
    acc = fmaf(w[i].w, xv.w, acc);
  }
  if constexpr (REM != 0) {
    if (tail) {
      const float4 xv = *reinterpret_cast<const float4*>(x + base + NFULL * 256);
      acc = fmaf(w[NFULL].x, xv.x, acc);
      acc = fmaf(w[NFULL].y, xv.y, acc);
      acc = fmaf(w[NFULL].z, xv.z, acc);
      acc = fmaf(w[NFULL].w, xv.w, acc);
    }
  }
  #pragma unroll
  for (int off = 32; off; off >>= 1) acc += __shfl_xor(acc, off, 64);
  return acc;
}

__global__ __launch_bounds__(NT)
void knet_kernel(const float* __restrict__ y, const float* __restrict__ m1x0,
                 const float* __restrict__ F, const float* __restrict__ Hm,
                 const float* __restrict__ h0,
                 const float* __restrict__ W1, const float* __restrict__ b1,
                 const float* __restrict__ Wi0, const float* __restrict__ Wh0,
                 const float* __restrict__ bi0, const float* __restrict__ bh0,
                 const float* __restrict__ Wi1, const float* __restrict__ Wh1,
                 const float* __restrict__ bi1, const float* __restrict__ bh1,
                 const float* __restrict__ W2, const float* __restrict__ b2,
                 const float* __restrict__ W3, const float* __restrict__ b3,
                 float* __restrict__ out, float* __restrict__ ws)
{
  const int blk = blockIdx.x, tid = threadIdx.x;
  const int wv = tid >> 6, ln = tid & 63;

  float* a_ws   = ws;            // 1600
  float* gi0_ws = ws + 1600;     // 6000
  float* gh0_ws = ws + 7600;     // 6000
  float* gi1_ws = ws + 13600;    // 6000
  float* gh1_ws = ws + 19600;    // 6000
  float* g_ws   = ws + 25600;    // 400
  unsigned* bar = (unsigned*)(ws + 26624);

  __shared__ __align__(16) float xs[2048];
  __shared__ __align__(16) float h1l[HID];   // block-local copy of h1 (identical in all blocks)
  __shared__ __align__(16) float h2l[HID];   // block-local copy of h2
  __shared__ float post_s[MM], prevpost_s[MM], prevprior_s[MM], prior_s[MM];
  __shared__ float dy_s[NN], yprev_s[NN], tmp_s[MM];
  __shared__ float d1_s[NN], d3_s[MM], d4_s[MM];
  __shared__ float kin_s[32], nrm_s[3];
  __shared__ float v_s[MM * NN], np_s[MM];

  // init block-local hidden state from h0 (read-only input, plain loads)
  for (int j = tid; j < HID; j += NT) { h1l[j] = h0[j]; h2l[j] = h0[HID + j]; }
  __syncthreads();

  unsigned bcnt = 0;

  for (int t = 0; t < TT; ++t) {
    // ---------------- Phase AE ----------------
    if (blk == NB - 1) {
      if (t > 0) {
        // finalize step t-1: v = W3@g + b3, new_post = prior + KG@dy
        stage_coh(g_ws, xs, H2, tid);
        __syncthreads();
        for (int r = wv; r < MM * NN; r += NW) {
          float acc = rowdotT<H2>(W3 + (size_t)r * H2, xs, ln);
          if (ln == 0) v_s[r] = acc + b3[r];
        }
        __syncthreads();
        if (tid < MM) {
          float np = prior_s[tid];
          #pragma unroll
          for (int j = 0; j < NN; ++j) np = fmaf(v_s[tid * NN + j], dy_s[j], np);
          out[tid * TT + (t - 1)] = np;
          np_s[tid] = np;
        }
        __syncthreads();
        if (tid < MM) {
          prevpost_s[tid]  = post_s[tid];
          prevprior_s[tid] = prior_s[tid];
          post_s[tid]      = np_s[tid];
        }
        __syncthreads();
      } else {
        if (tid < MM) {
          post_s[tid]      = m1x0[tid];
          prevpost_s[tid]  = 0.f;
          prevprior_s[tid] = m1x0[tid];
          float tv = 0.f;
          for (int j = 0; j < MM; ++j) tv = fmaf(F[tid * MM + j], m1x0[j], tv);
          tmp_s[tid] = tv;
        }
        __syncthreads();
        if (tid < NN) {
          float yp = 0.f;
          for (int j = 0; j < MM; ++j) yp = fmaf(Hm[tid * MM + j], tmp_s[j], yp);
          yprev_s[tid] = yp;
        }
        __syncthreads();
      }
      // features for step t
      if (tid < MM) {
        float pr = 0.f;
        for (int j = 0; j < MM; ++j) pr = fmaf(F[tid * MM + j], post_s[j], pr);
        prior_s[tid] = pr;
      }
      __syncthreads();
      if (tid < NN) {
        float my = 0.f;
        for (int j = 0; j < MM; ++j) my = fmaf(Hm[tid * MM + j], prior_s[j], my);
        float yt = y[tid * TT + t];
        dy_s[tid] = yt - my;
        d1_s[tid] = yt - ((t == 0) ? yprev_s[tid] : y[tid * TT + (t - 1)]);
        d3_s[tid] = post_s[tid] - prevpost_s[tid];
        d4_s[tid] = post_s[tid] - prevprior_s[tid];
      }
      __syncthreads();
      if (tid == 0) {
        float n1 = 0.f, n3 = 0.f, n4 = 0.f;
        for (int j = 0; j < NN; ++j) n1 += d1_s[j] * d1_s[j];
        for (int j = 0; j < MM; ++j) { n3 += d3_s[j] * d3_s[j]; n4 += d4_s[j] * d4_s[j]; }
        nrm_s[0] = fmaxf(sqrtf(n1), 1e-12f);
        nrm_s[1] = fmaxf(sqrtf(n3), 1e-12f);
        nrm_s[2] = fmaxf(sqrtf(n4), 1e-12f);
      }
      __syncthreads();
      if (tid < NN) kin_s[tid] = d1_s[tid] / nrm_s[0];
      if (tid < MM) {
        kin_s[NN + tid]      = d3_s[tid] / nrm_s[1];
        kin_s[NN + MM + tid] = d4_s[tid] / nrm_s[2];
      }
      __syncthreads();
      // a = relu(W1 @ kin + b1)
      for (int r = tid; r < H1; r += NT) {
        float acc = b1[r];
        const float* row = W1 + (size_t)r * 30;
        #pragma unroll
        for (int k = 0; k < 30; ++k) acc = fmaf(row[k], kin_s[k], acc);
        st_coh(a_ws + r, fmaxf(acc, 0.f));
      }
    } else {
      // gh0 = Wh0@h1 (blocks 0..126) ; gh1 = Wh1@h2 (blocks 127..254) — h in LDS
      if (blk < 127) {
        const int gw = blk * NW + wv;
        for (int r = gw; r < G3; r += 127 * NW) {
          float acc = rowdotT<HID>(Wh0 + (size_t)r * HID, h1l, ln);
          if (ln == 0) st_coh(gh0_ws + r, acc + bh0[r]);
        }
      } else {
        const int gw = (blk - 127) * NW + wv;
        for (int r = gw; r < G3; r += 128 * NW) {
          float acc = rowdotT<HID>(Wh1 + (size_t)r * HID, h2l, ln);
          if (ln == 0) st_coh(gh1_ws + r, acc + bh1[r]);
        }
      }
    }
    bcnt += NB; gridbar(bar, bcnt, tid);

    // ---------------- Phase B: gi0 = Wi0@a + bi0 ----------------
    stage_coh(a_ws, xs, H1, tid);
    __syncthreads();
    {
      const int gw = blk * NW + wv;
      for (int r = gw; r < G3; r += NB * NW) {
        float acc = rowdotT<H1>(Wi0 + (size_t)r * H1, xs, ln);
        if (ln == 0) st_coh(gi0_ws + r, acc + bi0[r]);
      }
    }
    bcnt += NB; gridbar(bar, bcnt, tid);

    // ---------------- Phase C: h1n (redundant, in LDS) then gi1 = Wi1@h1n ----------------
    {
      for (int j = tid; j < HID; j += NT) {
        float ir = ld_coh(gi0_ws + j),           hr = ld_coh(gh0_ws + j);
        float iz = ld_coh(gi0_ws + HID + j),     hz = ld_coh(gh0_ws + HID + j);
        float in_ = ld_coh(gi0_ws + 2 * HID + j), hn = ld_coh(gh0_ws + 2 * HID + j);
        float r = sigf(ir + hr);
        float z = sigf(iz + hz);
        float n = tanhfast(in_ + r * hn);
        h1l[j] = (1.f - z) * n + z * h1l[j];
      }
      __syncthreads();
      const int gw = blk * NW + wv;
      for (int r = gw; r < G3; r += NB * NW) {
        float acc = rowdotT<HID>(Wi1 + (size_t)r * HID, h1l, ln);
        if (ln == 0) st_coh(gi1_ws + r, acc + bi1[r]);
      }
    }
    bcnt += NB; gridbar(bar, bcnt, tid);

    // ---------------- Phase D: h2n (redundant, in LDS) then g = relu(W2@h2n) ----------------
    {
      for (int j = tid; j < HID; j += NT) {
        float ir = ld_coh(gi1_ws + j),           hr = ld_coh(gh1_ws + j);
        float iz = ld_coh(gi1_ws + HID + j),     hz = ld_coh(gh1_ws + HID + j);
        float in_ = ld_coh(gi1_ws + 2 * HID + j), hn = ld_coh(gh1_ws + 2 * HID + j);
        float r = sigf(ir + hr);
        float z = sigf(iz + hz);
        float n = tanhfast(in_ + r * hn);
        h2l[j] = (1.f - z) * n + z * h2l[j];
      }
      __syncthreads();
      if (blk < 25) {
        const int r = blk * NW + wv;               // 0..399, one row per wave
        float acc = rowdotT<HID>(W2 + (size_t)r * HID, h2l, ln);
        if (ln == 0) st_coh(g_ws + r, fmaxf(acc + b2[r], 0.f));
      }
    }
    bcnt += NB; gridbar(bar, bcnt, tid);
  }

  // ---------------- Tail: finalize step T-1 ----------------
  if (blk == NB - 1) {
    stage_coh(g_ws, xs, H2, tid);
    __syncthreads();
    for (int r = wv; r < MM * NN; r += NW) {
      float acc = rowdotT<H2>(W3 + (size_t)r * H2, xs, ln);
      if (ln == 0) v_s[r] = acc + b3[r];
    }
    __syncthreads();
    if (tid < MM) {
      float np = prior_s[tid];
      #pragma unroll
      for (int j = 0; j < NN; ++j) np = fmaf(v_s[tid * NN + j], dy_s[j], np);
      out[tid * TT + (TT - 1)] = np;
    }
  }
}

extern "C" void kernel_launch(void* const* d_in, const int* in_sizes, int n_in,
                              void* d_out, int out_size, void* d_ws, size_t ws_size,
                              hipStream_t stream) {
  const float* y    = (const float*)d_in[0];
  const float* m1x0 = (const float*)d_in[1];
  const float* F    = (const float*)d_in[2];
  const float* Hm   = (const float*)d_in[3];
  const float* h0   = (const float*)d_in[4];
  const float* W1   = (const float*)d_in[5];
  const float* b1   = (const float*)d_in[6];
  const float* Wi0  = (const float*)d_in[7];
  const float* Wh0  = (const float*)d_in[8];
  const float* bi0  = (const float*)d_in[9];
  const float* bh0  = (const float*)d_in[10];
  const float* Wi1  = (const float*)d_in[11];
  const float* Wh1  = (const float*)d_in[12];
  const float* bi1  = (const float*)d_in[13];
  const float* bh1  = (const float*)d_in[14];
  const float* W2   = (const float*)d_in[15];
  const float* b2   = (const float*)d_in[16];
  const float* W3   = (const float*)d_in[17];
  const float* b3   = (const float*)d_in[18];
  float* out = (float*)d_out;
  float* ws  = (float*)d_ws;

  // zero the barrier counter each launch (ws is NOT re-poisoned between replays)
  hipMemsetAsync((char*)d_ws + 26624 * sizeof(float), 0, 128, stream);

  void* args[] = { &y, &m1x0, &F, &Hm, &h0, &W1, &b1, &Wi0, &Wh0, &bi0, &bh0,
                   &Wi1, &Wh1, &bi1, &bh1, &W2, &b2, &W3, &b3, &out, &ws };
  hipLaunchCooperativeKernel((const void*)knet_kernel, dim3(NB), dim3(NT),
                             args, 0, stream);
}

// Round 4
// 5289.933 us; speedup vs baseline: 2.8583x; 1.1564x over previous
//
#include <hip/hip_runtime.h>
#include <math.h>

#define NB 256
#define NT 1024
#define NW 16      // waves per block
#define TT 100
#define MM 10
#define NN 10
#define HID 2000
#define H1 1600
#define H2 400
#define G3 6000    // 3*HID

#define SCOPE_AGENT __HIP_MEMORY_SCOPE_AGENT

__device__ __forceinline__ float sigf(float x) { return 1.f / (1.f + __expf(-x)); }
__device__ __forceinline__ float tanhfast(float x) { return 2.f / (1.f + __expf(-2.f * x)) - 1.f; }

// ---- cross-XCD coherent access (bypass non-coherent L2, no fences) ----
__device__ __forceinline__ float ld_coh(const float* p) {
  return __hip_atomic_load(p, __ATOMIC_RELAXED, SCOPE_AGENT);
}
__device__ __forceinline__ void st_coh(float* p, float v) {
  __hip_atomic_store(p, v, __ATOMIC_RELAXED, SCOPE_AGENT);
}
__device__ __forceinline__ float2 ld_coh2(const float* p) {
  unsigned long long v = __hip_atomic_load((const unsigned long long*)p,
                                           __ATOMIC_RELAXED, SCOPE_AGENT);
  union { unsigned long long u; float2 f; } c; c.u = v; return c.f;
}
// stage n floats (n even, 8B-aligned src) from coherent global into LDS
__device__ __forceinline__ void stage_coh(const float* __restrict__ src,
                                          float* __restrict__ dst, int n, int tid) {
  const int n2 = n >> 1;
  for (int j = tid; j < n2; j += NT) {
    float2 v = ld_coh2(src + 2 * j);
    dst[2 * j]     = v.x;
    dst[2 * j + 1] = v.y;
  }
}

// ---- distributed flag barrier: per-block slot (stride 4), all-poll-all ----
// No RMW contention: one relaxed store per block, 256 parallel pollers/block
// each watching a distinct address. __syncthreads() before the store drains
// vmcnt(0), so all prior agent-scope data stores are at the coherence point.
__device__ __forceinline__ void gridbar(unsigned* flags, unsigned ep, int tid, int blk) {
  __syncthreads();
  if (tid == 0)
    __hip_atomic_store(flags + blk * 4, ep, __ATOMIC_RELAXED, SCOPE_AGENT);
  if (tid < NB) {
    while (__hip_atomic_load(flags + tid * 4, __ATOMIC_RELAXED, SCOPE_AGENT) < ep) { }
  }
  __syncthreads();
}

// one row dot-product per wave; x in LDS; K compile-time
template<int K>
__device__ __forceinline__ float rowdotT(const float* __restrict__ row,
                                         const float* __restrict__ x, int ln) {
  constexpr int NFULL = K / 256;
  constexpr int REM   = K - NFULL * 256;
  const int base = ln * 4;
  float4 w[NFULL + (REM ? 1 : 0)];
  #pragma unroll
  for (int i = 0; i < NFULL; ++i)
    w[i] = *reinterpret_cast<const float4*>(row + base + i * 256);
  bool tail = false;
  if constexpr (REM != 0) {
    tail = (base + NFULL * 256 + 3 < K);
    if (tail) w[NFULL] = *reinterpret_cast<const float4*>(row + base + NFULL * 256);
  }
  float acc = 0.f;
  #pragma unroll
  for (int i = 0; i < NFULL; ++i) {
    const float4 xv = *reinterpret_cast<const float4*>(x + base + i * 256);
    acc = fmaf(w[i].x, xv.x, acc);
    acc = fmaf(w[i].y, xv.y, acc);
    acc = fmaf(w[i].z, xv.z, acc);
    acc = fmaf(w[i].w, xv.w, acc);
  }
  if constexpr (REM != 0) {
    if (tail) {
      const float4 xv = *reinterpret_cast<const float4*>(x + base + NFULL * 256);
      acc = fmaf(w[NFULL].x, xv.x, acc);
      acc = fmaf(w[NFULL].y, xv.y, acc);
      acc = fmaf(w[NFULL].z, xv.z, acc);
      acc = fmaf(w[NFULL].w, xv.w, acc);
    }
  }
  #pragma unroll
  for (int off = 32; off; off >>= 1) acc += __shfl_xor(acc, off, 64);
  return acc;
}

__global__ __launch_bounds__(NT)
void knet_kernel(const float* __restrict__ y, const float* __restrict__ m1x0,
                 const float* __restrict__ F, const float* __restrict__ Hm,
                 const float* __restrict__ h0,
                 const float* __restrict__ W1, const float* __restrict__ b1,
                 const float* __restrict__ Wi0, const float* __restrict__ Wh0,
                 const float* __restrict__ bi0, const float* __restrict__ bh0,
                 const float* __restrict__ Wi1, const float* __restrict__ Wh1,
                 const float* __restrict__ bi1, const float* __restrict__ bh1,
                 const float* __restrict__ W2, const float* __restrict__ b2,
                 const float* __restrict__ W3, const float* __restrict__ b3,
                 float* __restrict__ out, float* __restrict__ ws)
{
  const int blk = blockIdx.x, tid = threadIdx.x;
  const int wv = tid >> 6, ln = tid & 63;

  float* a_ws   = ws;            // 1600
  float* gi0_ws = ws + 1600;     // 6000
  float* gh0_ws = ws + 7600;     // 6000
  float* gi1_ws = ws + 13600;    // 6000
  float* gh1_ws = ws + 19600;    // 6000
  float* g_ws   = ws + 25600;    // 400
  unsigned* flags = (unsigned*)(ws + 26624);   // 256 slots, stride 4 uints

  __shared__ __align__(16) float xs[1664];
  __shared__ __align__(16) float h1l[HID];   // block-local h1 (identical in all blocks)
  __shared__ __align__(16) float h2l[HID];   // block-local h2
  __shared__ float post_s[MM], prevpost_s[MM], prevprior_s[MM], prior_s[MM];
  __shared__ float dy_s[NN], yprev_s[NN], tmp_s[MM];
  __shared__ float d1_s[NN], d3_s[MM], d4_s[MM];
  __shared__ float kin_s[32], nrm_s[3];
  __shared__ float v_s[MM * NN], np_s[MM];

  for (int j = tid; j < HID; j += NT) { h1l[j] = h0[j]; h2l[j] = h0[HID + j]; }
  __syncthreads();

  unsigned ep = 0;

  for (int t = 0; t < TT; ++t) {
    // ---- P1: Wh1@h2 (blocks 0..254; + Wh0@h1 prologue at t==0); serial on 255 ----
    if (blk == NB - 1) {
      if (t > 0) {
        // finalize step t-1: v = W3@g + b3, new_post = prior + KG@dy
        stage_coh(g_ws, xs, H2, tid);
        __syncthreads();
        for (int r = wv; r < MM * NN; r += NW) {
          float acc = rowdotT<H2>(W3 + (size_t)r * H2, xs, ln);
          if (ln == 0) v_s[r] = acc + b3[r];
        }
        __syncthreads();
        if (tid < MM) {
          float np = prior_s[tid];
          #pragma unroll
          for (int j = 0; j < NN; ++j) np = fmaf(v_s[tid * NN + j], dy_s[j], np);
          out[tid * TT + (t - 1)] = np;
          np_s[tid] = np;
        }
        __syncthreads();
        if (tid < MM) {
          prevpost_s[tid]  = post_s[tid];
          prevprior_s[tid] = prior_s[tid];
          post_s[tid]      = np_s[tid];
        }
        __syncthreads();
      } else {
        if (tid < MM) {
          post_s[tid]      = m1x0[tid];
          prevpost_s[tid]  = 0.f;
          prevprior_s[tid] = m1x0[tid];
          float tv = 0.f;
          for (int j = 0; j < MM; ++j) tv = fmaf(F[tid * MM + j], m1x0[j], tv);
          tmp_s[tid] = tv;
        }
        __syncthreads();
        if (tid < NN) {
          float yp = 0.f;
          for (int j = 0; j < MM; ++j) yp = fmaf(Hm[tid * MM + j], tmp_s[j], yp);
          yprev_s[tid] = yp;
        }
        __syncthreads();
      }
      // features for step t
      if (tid < MM) {
        float pr = 0.f;
        for (int j = 0; j < MM; ++j) pr = fmaf(F[tid * MM + j], post_s[j], pr);
        prior_s[tid] = pr;
      }
      __syncthreads();
      if (tid < NN) {
        float my = 0.f;
        for (int j = 0; j < MM; ++j) my = fmaf(Hm[tid * MM + j], prior_s[j], my);
        float yt = y[tid * TT + t];
        dy_s[tid] = yt - my;
        d1_s[tid] = yt - ((t == 0) ? yprev_s[tid] : y[tid * TT + (t - 1)]);
        d3_s[tid] = post_s[tid] - prevpost_s[tid];
        d4_s[tid] = post_s[tid] - prevprior_s[tid];
      }
      __syncthreads();
      if (tid == 0) {
        float n1 = 0.f, n3 = 0.f, n4 = 0.f;
        for (int j = 0; j < NN; ++j) n1 += d1_s[j] * d1_s[j];
        for (int j = 0; j < MM; ++j) { n3 += d3_s[j] * d3_s[j]; n4 += d4_s[j] * d4_s[j]; }
        nrm_s[0] = fmaxf(sqrtf(n1), 1e-12f);
        nrm_s[1] = fmaxf(sqrtf(n3), 1e-12f);
        nrm_s[2] = fmaxf(sqrtf(n4), 1e-12f);
      }
      __syncthreads();
      if (tid < NN) kin_s[tid] = d1_s[tid] / nrm_s[0];
      if (tid < MM) {
        kin_s[NN + tid]      = d3_s[tid] / nrm_s[1];
        kin_s[NN + MM + tid] = d4_s[tid] / nrm_s[2];
      }
      __syncthreads();
      // a = relu(W1 @ kin + b1)
      for (int r = tid; r < H1; r += NT) {
        float acc = b1[r];
        const float* row = W1 + (size_t)r * 30;
        #pragma unroll
        for (int k = 0; k < 30; ++k) acc = fmaf(row[k], kin_s[k], acc);
        st_coh(a_ws + r, fmaxf(acc, 0.f));
      }
    } else {
      const int gw = blk * NW + wv;                // 0..4079
      for (int r = gw; r < G3; r += (NB - 1) * NW) {
        float acc = rowdotT<HID>(Wh1 + (size_t)r * HID, h2l, ln);
        if (ln == 0) st_coh(gh1_ws + r, acc + bh1[r]);
      }
      if (t == 0) {   // prologue: gh0 for step 0 (steady-state it comes from P4)
        for (int r = gw; r < G3; r += (NB - 1) * NW) {
          float acc = rowdotT<HID>(Wh0 + (size_t)r * HID, h1l, ln);
          if (ln == 0) st_coh(gh0_ws + r, acc + bh0[r]);
        }
      }
    }
    ++ep; gridbar(flags, ep, tid, blk);

    // ---- P2: gi0 = Wi0@a + bi0 (all blocks) ----
    stage_coh(a_ws, xs, H1, tid);
    __syncthreads();
    {
      const int gw = blk * NW + wv;
      for (int r = gw; r < G3; r += NB * NW) {
        float acc = rowdotT<H1>(Wi0 + (size_t)r * H1, xs, ln);
        if (ln == 0) st_coh(gi0_ws + r, acc + bi0[r]);
      }
    }
    ++ep; gridbar(flags, ep, tid, blk);

    // ---- P3: combine1 (all, redundant, in LDS) then gi1 = Wi1@h1n ----
    {
      for (int j = tid; j < HID / 2; j += NT) {
        float2 ir = ld_coh2(gi0_ws + 2 * j),           hr = ld_coh2(gh0_ws + 2 * j);
        float2 iz = ld_coh2(gi0_ws + HID + 2 * j),     hz = ld_coh2(gh0_ws + HID + 2 * j);
        float2 in_ = ld_coh2(gi0_ws + 2 * HID + 2 * j), hn = ld_coh2(gh0_ws + 2 * HID + 2 * j);
        float r0 = sigf(ir.x + hr.x), r1 = sigf(ir.y + hr.y);
        float z0 = sigf(iz.x + hz.x), z1 = sigf(iz.y + hz.y);
        float n0 = tanhfast(in_.x + r0 * hn.x), n1 = tanhfast(in_.y + r1 * hn.y);
        h1l[2 * j]     = (1.f - z0) * n0 + z0 * h1l[2 * j];
        h1l[2 * j + 1] = (1.f - z1) * n1 + z1 * h1l[2 * j + 1];
      }
      __syncthreads();
      const int gw = blk * NW + wv;
      for (int r = gw; r < G3; r += NB * NW) {
        float acc = rowdotT<HID>(Wi1 + (size_t)r * HID, h1l, ln);
        if (ln == 0) st_coh(gi1_ws + r, acc + bi1[r]);
      }
    }
    ++ep; gridbar(flags, ep, tid, blk);

    // ---- P4: combine2 (all) then rows 0..6399: W2@h2n (r<400) | Wh0@h1n next step ----
    {
      for (int j = tid; j < HID / 2; j += NT) {
        float2 ir = ld_coh2(gi1_ws + 2 * j),           hr = ld_coh2(gh1_ws + 2 * j);
        float2 iz = ld_coh2(gi1_ws + HID + 2 * j),     hz = ld_coh2(gh1_ws + HID + 2 * j);
        float2 in_ = ld_coh2(gi1_ws + 2 * HID + 2 * j), hn = ld_coh2(gh1_ws + 2 * HID + 2 * j);
        float r0 = sigf(ir.x + hr.x), r1 = sigf(ir.y + hr.y);
        float z0 = sigf(iz.x + hz.x), z1 = sigf(iz.y + hz.y);
        float n0 = tanhfast(in_.x + r0 * hn.x), n1 = tanhfast(in_.y + r1 * hn.y);
        h2l[2 * j]     = (1.f - z0) * n0 + z0 * h2l[2 * j];
        h2l[2 * j + 1] = (1.f - z1) * n1 + z1 * h2l[2 * j + 1];
      }
      __syncthreads();
      const int gw = blk * NW + wv;
      for (int r = gw; r < H2 + G3; r += NB * NW) {
        if (r < H2) {
          float acc = rowdotT<HID>(W2 + (size_t)r * HID, h2l, ln);
          if (ln == 0) st_coh(g_ws + r, fmaxf(acc + b2[r], 0.f));
        } else {
          const int rr = r - H2;
          float acc = rowdotT<HID>(Wh0 + (size_t)rr * HID, h1l, ln);
          if (ln == 0) st_coh(gh0_ws + rr, acc + bh0[rr]);
        }
      }
    }
    ++ep; gridbar(flags, ep, tid, blk);
  }

  // ---------------- Tail: finalize step T-1 ----------------
  if (blk == NB - 1) {
    stage_coh(g_ws, xs, H2, tid);
    __syncthreads();
    for (int r = wv; r < MM * NN; r += NW) {
      float acc = rowdotT<H2>(W3 + (size_t)r * H2, xs, ln);
      if (ln == 0) v_s[r] = acc + b3[r];
    }
    __syncthreads();
    if (tid < MM) {
      float np = prior_s[tid];
      #pragma unroll
      for (int j = 0; j < NN; ++j) np = fmaf(v_s[tid * NN + j], dy_s[j], np);
      out[tid * TT + (TT - 1)] = np;
    }
  }
}

extern "C" void kernel_launch(void* const* d_in, const int* in_sizes, int n_in,
                              void* d_out, int out_size, void* d_ws, size_t ws_size,
                              hipStream_t stream) {
  const float* y    = (const float*)d_in[0];
  const float* m1x0 = (const float*)d_in[1];
  const float* F    = (const float*)d_in[2];
  const float* Hm   = (const float*)d_in[3];
  const float* h0   = (const float*)d_in[4];
  const float* W1   = (const float*)d_in[5];
  const float* b1   = (const float*)d_in[6];
  const float* Wi0  = (const float*)d_in[7];
  const float* Wh0  = (const float*)d_in[8];
  const float* bi0  = (const float*)d_in[9];
  const float* bh0  = (const float*)d_in[10];
  const float* Wi1  = (const float*)d_in[11];
  const float* Wh1  = (const float*)d_in[12];
  const float* bi1  = (const float*)d_in[13];
  const float* bh1  = (const float*)d_in[14];
  const float* W2   = (const float*)d_in[15];
  const float* b2   = (const float*)d_in[16];
  const float* W3   = (const float*)d_in[17];
  const float* b3   = (const float*)d_in[18];
  float* out = (float*)d_out;
  float* ws  = (float*)d_ws;

  // zero the barrier flags each launch (monotone epochs start at 1)
  hipMemsetAsync((char*)d_ws + 26624 * sizeof(float), 0, 4096, stream);

  void* args[] = { &y, &m1x0, &F, &Hm, &h0, &W1, &b1, &Wi0, &Wh0, &bi0, &bh0,
                   &Wi1, &Wh1, &bi1, &bh1, &W2, &b2, &W3, &b3, &out, &ws };
  hipLaunchCooperativeKernel((const void*)knet_kernel, dim3(NB), dim3(NT),
                             args, 0, stream);
}

// Round 5
// 4922.667 us; speedup vs baseline: 3.0715x; 1.0746x over previous
//
#include <hip/hip_runtime.h>
#include <math.h>

#define NB 256
#define NT 1024
#define NW 16      // waves per block
#define TT 100
#define MM 10
#define NN 10
#define HID 2000
#define H1 1600
#define H2 400
#define G3 6000    // 3*HID

#define SCOPE_AGENT __HIP_MEMORY_SCOPE_AGENT

__device__ __forceinline__ float sigf(float x) { return 1.f / (1.f + __expf(-x)); }
__device__ __forceinline__ float tanhfast(float x) { return 2.f / (1.f + __expf(-2.f * x)) - 1.f; }

// ---- cross-XCD coherent access (bypass non-coherent L2, no fences) ----
__device__ __forceinline__ float ld_coh(const float* p) {
  return __hip_atomic_load(p, __ATOMIC_RELAXED, SCOPE_AGENT);
}
__device__ __forceinline__ void st_coh(float* p, float v) {
  __hip_atomic_store(p, v, __ATOMIC_RELAXED, SCOPE_AGENT);
}
__device__ __forceinline__ float2 ld_coh2(const float* p) {
  unsigned long long v = __hip_atomic_load((const unsigned long long*)p,
                                           __ATOMIC_RELAXED, SCOPE_AGENT);
  union { unsigned long long u; float2 f; } c; c.u = v; return c.f;
}
// stage n floats (n even, 8B-aligned src) from coherent global into LDS
__device__ __forceinline__ void stage_coh(const float* __restrict__ src,
                                          float* __restrict__ dst, int n, int tid) {
  const int n2 = n >> 1;
  for (int j = tid; j < n2; j += NT) {
    float2 v = ld_coh2(src + 2 * j);
    dst[2 * j]     = v.x;
    dst[2 * j + 1] = v.y;
  }
}

// ---- two-level grid barrier: per-block arrival slots + single release word ----
// Arrival: block's tid0 stores epoch to its own 64B-strided slot (no RMW).
// Block 0 alone polls all 256 slots (s_sleep-throttled), then publishes the
// epoch to one release word. Other blocks poll ONLY that word with ONE thread.
// Poll traffic ~100x lower than all-poll-all; coherence-point visibility chain
// is identical to the validated rounds-3/4 scheme.
__device__ __forceinline__ void gridbar(unsigned* flags, unsigned* release,
                                        unsigned ep, int tid, int blk) {
  __syncthreads();   // drains vmcnt(0): prior coherent stores are at coherence point
  if (tid == 0)
    __hip_atomic_store(flags + blk * 16, ep, __ATOMIC_RELAXED, SCOPE_AGENT);
  if (blk == 0) {
    if (tid < NB) {
      while (__hip_atomic_load(flags + tid * 16, __ATOMIC_RELAXED, SCOPE_AGENT) < ep)
        __builtin_amdgcn_s_sleep(1);
    }
    __syncthreads();
    if (tid == 0)
      __hip_atomic_store(release, ep, __ATOMIC_RELAXED, SCOPE_AGENT);
  } else {
    if (tid == 0) {
      while (__hip_atomic_load(release, __ATOMIC_RELAXED, SCOPE_AGENT) < ep)
        __builtin_amdgcn_s_sleep(1);
    }
  }
  __syncthreads();
}

// one row dot-product per wave; x in LDS; K compile-time
template<int K>
__device__ __forceinline__ float rowdotT(const float* __restrict__ row,
                                         const float* __restrict__ x, int ln) {
  constexpr int NFULL = K / 256;
  constexpr int REM   = K - NFULL * 256;
  const int base = ln * 4;
  float4 w[NFULL + (REM ? 1 : 0)];
  #pragma unroll
  for (int i = 0; i < NFULL; ++i)
    w[i] = *reinterpret_cast<const float4*>(row + base + i * 256);
  bool tail = false;
  if constexpr (REM != 0) {
    tail = (base + NFULL * 256 + 3 < K);
    if (tail) w[NFULL] = *reinterpret_cast<const float4*>(row + base + NFULL * 256);
  }
  float acc = 0.f;
  #pragma unroll
  for (int i = 0; i < NFULL; ++i) {
    const float4 xv = *reinterpret_cast<const float4*>(x + base + i * 256);
    acc = fmaf(w[i].x, xv.x, acc);
    acc = fmaf(w[i].y, xv.y, acc);
    acc = fmaf(w[i].z, xv.z, acc);
    acc = fmaf(w[i].w, xv.w, acc);
  }
  if constexpr (REM != 0) {
    if (tail) {
      const float4 xv = *reinterpret_cast<const float4*>(x + base + NFULL * 256);
      acc = fmaf(w[NFULL].x, xv.x, acc);
      acc = fmaf(w[NFULL].y, xv.y, acc);
      acc = fmaf(w[NFULL].z, xv.z, acc);
      acc = fmaf(w[NFULL].w, xv.w, acc);
    }
  }
  #pragma unroll
  for (int off = 32; off; off >>= 1) acc += __shfl_xor(acc, off, 64);
  return acc;
}

__global__ __launch_bounds__(NT)
void knet_kernel(const float* __restrict__ y, const float* __restrict__ m1x0,
                 const float* __restrict__ F, const float* __restrict__ Hm,
                 const float* __restrict__ h0,
                 const float* __restrict__ W1, const float* __restrict__ b1,
                 const float* __restrict__ Wi0, const float* __restrict__ Wh0,
                 const float* __restrict__ bi0, const float* __restrict__ bh0,
                 const float* __restrict__ Wi1, const float* __restrict__ Wh1,
                 const float* __restrict__ bi1, const float* __restrict__ bh1,
                 const float* __restrict__ W2, const float* __restrict__ b2,
                 const float* __restrict__ W3, const float* __restrict__ b3,
                 float* __restrict__ out, float* __restrict__ ws)
{
  const int blk = blockIdx.x, tid = threadIdx.x;
  const int wv = tid >> 6, ln = tid & 63;

  float* a_ws   = ws;            // 1600
  float* gi0_ws = ws + 1600;     // 6000
  float* gh0_ws = ws + 7600;     // 6000
  float* gi1_ws = ws + 13600;    // 6000
  float* gh1_ws = ws + 19600;    // 6000
  float* g_ws   = ws + 25600;    // 400
  unsigned* flags   = (unsigned*)(ws + 26624);   // 256 slots, 64B stride
  unsigned* release = flags + NB * 16;           // single release word

  __shared__ __align__(16) float xs[1664];
  __shared__ __align__(16) float h1l[HID];   // block-local h1 (identical in all blocks)
  __shared__ __align__(16) float h2l[HID];   // block-local h2
  __shared__ float post_s[MM], prevpost_s[MM], prevprior_s[MM], prior_s[MM];
  __shared__ float dy_s[NN], yprev_s[NN], tmp_s[MM];
  __shared__ float d1_s[NN], d3_s[MM], d4_s[MM];
  __shared__ float kin_s[32], nrm_s[3];
  __shared__ float v_s[MM * NN], np_s[MM];

  for (int j = tid; j < HID; j += NT) { h1l[j] = h0[j]; h2l[j] = h0[HID + j]; }
  __syncthreads();

  unsigned ep = 0;

  for (int t = 0; t < TT; ++t) {
    // ---- P1: Wh1@h2 (blocks 0..254; + Wh0@h1 prologue at t==0); serial on 255 ----
    if (blk == NB - 1) {
      if (t > 0) {
        // finalize step t-1: v = W3@g + b3, new_post = prior + KG@dy
        stage_coh(g_ws, xs, H2, tid);
        __syncthreads();
        for (int r = wv; r < MM * NN; r += NW) {
          float acc = rowdotT<H2>(W3 + (size_t)r * H2, xs, ln);
          if (ln == 0) v_s[r] = acc + b3[r];
        }
        __syncthreads();
        if (tid < MM) {
          float np = prior_s[tid];
          #pragma unroll
          for (int j = 0; j < NN; ++j) np = fmaf(v_s[tid * NN + j], dy_s[j], np);
          out[tid * TT + (t - 1)] = np;
          np_s[tid] = np;
        }
        __syncthreads();
        if (tid < MM) {
          prevpost_s[tid]  = post_s[tid];
          prevprior_s[tid] = prior_s[tid];
          post_s[tid]      = np_s[tid];
        }
        __syncthreads();
      } else {
        if (tid < MM) {
          post_s[tid]      = m1x0[tid];
          prevpost_s[tid]  = 0.f;
          prevprior_s[tid] = m1x0[tid];
          float tv = 0.f;
          for (int j = 0; j < MM; ++j) tv = fmaf(F[tid * MM + j], m1x0[j], tv);
          tmp_s[tid] = tv;
        }
        __syncthreads();
        if (tid < NN) {
          float yp = 0.f;
          for (int j = 0; j < MM; ++j) yp = fmaf(Hm[tid * MM + j], tmp_s[j], yp);
          yprev_s[tid] = yp;
        }
        __syncthreads();
      }
      // features for step t
      if (tid < MM) {
        float pr = 0.f;
        for (int j = 0; j < MM; ++j) pr = fmaf(F[tid * MM + j], post_s[j], pr);
        prior_s[tid] = pr;
      }
      __syncthreads();
      if (tid < NN) {
        float my = 0.f;
        for (int j = 0; j < MM; ++j) my = fmaf(Hm[tid * MM + j], prior_s[j], my);
        float yt = y[tid * TT + t];
        dy_s[tid] = yt - my;
        d1_s[tid] = yt - ((t == 0) ? yprev_s[tid] : y[tid * TT + (t - 1)]);
        d3_s[tid] = post_s[tid] - prevpost_s[tid];
        d4_s[tid] = post_s[tid] - prevprior_s[tid];
      }
      __syncthreads();
      if (tid == 0) {
        float n1 = 0.f, n3 = 0.f, n4 = 0.f;
        for (int j = 0; j < NN; ++j) n1 += d1_s[j] * d1_s[j];
        for (int j = 0; j < MM; ++j) { n3 += d3_s[j] * d3_s[j]; n4 += d4_s[j] * d4_s[j]; }
        nrm_s[0] = fmaxf(sqrtf(n1), 1e-12f);
        nrm_s[1] = fmaxf(sqrtf(n3), 1e-12f);
        nrm_s[2] = fmaxf(sqrtf(n4), 1e-12f);
      }
      __syncthreads();
      if (tid < NN) kin_s[tid] = d1_s[tid] / nrm_s[0];
      if (tid < MM) {
        kin_s[NN + tid]      = d3_s[tid] / nrm_s[1];
        kin_s[NN + MM + tid] = d4_s[tid] / nrm_s[2];
      }
      __syncthreads();
      // a = relu(W1 @ kin + b1)
      for (int r = tid; r < H1; r += NT) {
        float acc = b1[r];
        const float* row = W1 + (size_t)r * 30;
        #pragma unroll
        for (int k = 0; k < 30; ++k) acc = fmaf(row[k], kin_s[k], acc);
        st_coh(a_ws + r, fmaxf(acc, 0.f));
      }
    } else {
      const int gw = blk * NW + wv;                // 0..4079
      for (int r = gw; r < G3; r += (NB - 1) * NW) {
        float acc = rowdotT<HID>(Wh1 + (size_t)r * HID, h2l, ln);
        if (ln == 0) st_coh(gh1_ws + r, acc + bh1[r]);
      }
      if (t == 0) {   // prologue: gh0 for step 0 (steady-state it comes from P4)
        for (int r = gw; r < G3; r += (NB - 1) * NW) {
          float acc = rowdotT<HID>(Wh0 + (size_t)r * HID, h1l, ln);
          if (ln == 0) st_coh(gh0_ws + r, acc + bh0[r]);
        }
      }
    }
    ++ep; gridbar(flags, release, ep, tid, blk);

    // ---- P2: gi0 = Wi0@a + bi0 (all blocks) ----
    stage_coh(a_ws, xs, H1, tid);
    __syncthreads();
    {
      const int gw = blk * NW + wv;
      for (int r = gw; r < G3; r += NB * NW) {
        float acc = rowdotT<H1>(Wi0 + (size_t)r * H1, xs, ln);
        if (ln == 0) st_coh(gi0_ws + r, acc + bi0[r]);
      }
    }
    ++ep; gridbar(flags, release, ep, tid, blk);

    // ---- P3: combine1 (all, redundant, in LDS) then gi1 = Wi1@h1n ----
    {
      for (int j = tid; j < HID / 2; j += NT) {
        float2 ir = ld_coh2(gi0_ws + 2 * j),           hr = ld_coh2(gh0_ws + 2 * j);
        float2 iz = ld_coh2(gi0_ws + HID + 2 * j),     hz = ld_coh2(gh0_ws + HID + 2 * j);
        float2 in_ = ld_coh2(gi0_ws + 2 * HID + 2 * j), hn = ld_coh2(gh0_ws + 2 * HID + 2 * j);
        float r0 = sigf(ir.x + hr.x), r1 = sigf(ir.y + hr.y);
        float z0 = sigf(iz.x + hz.x), z1 = sigf(iz.y + hz.y);
        float n0 = tanhfast(in_.x + r0 * hn.x), n1 = tanhfast(in_.y + r1 * hn.y);
        h1l[2 * j]     = (1.f - z0) * n0 + z0 * h1l[2 * j];
        h1l[2 * j + 1] = (1.f - z1) * n1 + z1 * h1l[2 * j + 1];
      }
      __syncthreads();
      const int gw = blk * NW + wv;
      for (int r = gw; r < G3; r += NB * NW) {
        float acc = rowdotT<HID>(Wi1 + (size_t)r * HID, h1l, ln);
        if (ln == 0) st_coh(gi1_ws + r, acc + bi1[r]);
      }
    }
    ++ep; gridbar(flags, release, ep, tid, blk);

    // ---- P4: combine2 (all) then rows 0..6399: W2@h2n (r<400) | Wh0@h1n next step ----
    {
      for (int j = tid; j < HID / 2; j += NT) {
        float2 ir = ld_coh2(gi1_ws + 2 * j),           hr = ld_coh2(gh1_ws + 2 * j);
        float2 iz = ld_coh2(gi1_ws + HID + 2 * j),     hz = ld_coh2(gh1_ws + HID + 2 * j);
        float2 in_ = ld_coh2(gi1_ws + 2 * HID + 2 * j), hn = ld_coh2(gh1_ws + 2 * HID + 2 * j);
        float r0 = sigf(ir.x + hr.x), r1 = sigf(ir.y + hr.y);
        float z0 = sigf(iz.x + hz.x), z1 = sigf(iz.y + hz.y);
        float n0 = tanhfast(in_.x + r0 * hn.x), n1 = tanhfast(in_.y + r1 * hn.y);
        h2l[2 * j]     = (1.f - z0) * n0 + z0 * h2l[2 * j];
        h2l[2 * j + 1] = (1.f - z1) * n1 + z1 * h2l[2 * j + 1];
      }
      __syncthreads();
      const int gw = blk * NW + wv;
      for (int r = gw; r < H2 + G3; r += NB * NW) {
        if (r < H2) {
          float acc = rowdotT<HID>(W2 + (size_t)r * HID, h2l, ln);
          if (ln == 0) st_coh(g_ws + r, fmaxf(acc + b2[r], 0.f));
        } else {
          const int rr = r - H2;
          float acc = rowdotT<HID>(Wh0 + (size_t)rr * HID, h1l, ln);
          if (ln == 0) st_coh(gh0_ws + rr, acc + bh0[rr]);
        }
      }
    }
    ++ep; gridbar(flags, release, ep, tid, blk);
  }

  // ---------------- Tail: finalize step T-1 ----------------
  if (blk == NB - 1) {
    stage_coh(g_ws, xs, H2, tid);
    __syncthreads();
    for (int r = wv; r < MM * NN; r += NW) {
      float acc = rowdotT<H2>(W3 + (size_t)r * H2, xs, ln);
      if (ln == 0) v_s[r] = acc + b3[r];
    }
    __syncthreads();
    if (tid < MM) {
      float np = prior_s[tid];
      #pragma unroll
      for (int j = 0; j < NN; ++j) np = fmaf(v_s[tid * NN + j], dy_s[j], np);
      out[tid * TT + (TT - 1)] = np;
    }
  }
}

extern "C" void kernel_launch(void* const* d_in, const int* in_sizes, int n_in,
                              void* d_out, int out_size, void* d_ws, size_t ws_size,
                              hipStream_t stream) {
  const float* y    = (const float*)d_in[0];
  const float* m1x0 = (const float*)d_in[1];
  const float* F    = (const float*)d_in[2];
  const float* Hm   = (const float*)d_in[3];
  const float* h0   = (const float*)d_in[4];
  const float* W1   = (const float*)d_in[5];
  const float* b1   = (const float*)d_in[6];
  const float* Wi0  = (const float*)d_in[7];
  const float* Wh0  = (const float*)d_in[8];
  const float* bi0  = (const float*)d_in[9];
  const float* bh0  = (const float*)d_in[10];
  const float* Wi1  = (const float*)d_in[11];
  const float* Wh1  = (const float*)d_in[12];
  const float* bi1  = (const float*)d_in[13];
  const float* bh1  = (const float*)d_in[14];
  const float* W2   = (const float*)d_in[15];
  const float* b2   = (const float*)d_in[16];
  const float* W3   = (const float*)d_in[17];
  const float* b3   = (const float*)d_in[18];
  float* out = (float*)d_out;
  float* ws  = (float*)d_ws;

  // zero arrival flags (256 x 64B) + release word each launch (epochs restart at 1)
  hipMemsetAsync((char*)d_ws + 26624 * sizeof(float), 0, NB * 64 + 64, stream);

  void* args[] = { &y, &m1x0, &F, &Hm, &h0, &W1, &b1, &Wi0, &Wh0, &bi0, &bh0,
                   &Wi1, &Wh1, &bi1, &bh1, &W2, &b2, &W3, &b3, &out, &ws };
  hipLaunchCooperativeKernel((const void*)knet_kernel, dim3(NB), dim3(NT),
                             args, 0, stream);
}

// Round 6
// 4338.403 us; speedup vs baseline: 3.4852x; 1.1347x over previous
//
#include <hip/hip_runtime.h>
#include <math.h>

#define NB 256
#define NT 1024
#define NW 16      // waves per block
#define TT 100
#define MM 10
#define NN 10
#define HID 2000
#define H1 1600
#define H2 400
#define G3 6000    // 3*HID
#define KP 2048    // padded K for fp16 weights
#define RPB 24     // rows per block-task

#define SCOPE_AGENT __HIP_MEMORY_SCOPE_AGENT

typedef _Float16 h2v __attribute__((ext_vector_type(2)));

__device__ __forceinline__ float sigf(float x) { return 1.f / (1.f + __expf(-x)); }
__device__ __forceinline__ float tanhfast(float x) { return 2.f / (1.f + __expf(-2.f * x)) - 1.f; }

// ---- cross-XCD coherent access (bypass non-coherent L2, no fences) ----
__device__ __forceinline__ float ld_coh(const float* p) {
  return __hip_atomic_load(p, __ATOMIC_RELAXED, SCOPE_AGENT);
}
__device__ __forceinline__ void st_coh(float* p, float v) {
  __hip_atomic_store(p, v, __ATOMIC_RELAXED, SCOPE_AGENT);
}
__device__ __forceinline__ float2 ld_coh2(const float* p) {
  unsigned long long v = __hip_atomic_load((const unsigned long long*)p,
                                           __ATOMIC_RELAXED, SCOPE_AGENT);
  union { unsigned long long u; float2 f; } c; c.u = v; return c.f;
}
__device__ __forceinline__ void stage_coh(const float* __restrict__ src,
                                          float* __restrict__ dst, int n, int tid) {
  const int n2 = n >> 1;
  for (int j = tid; j < n2; j += NT) {
    float2 v = ld_coh2(src + 2 * j);
    dst[2 * j]     = v.x;
    dst[2 * j + 1] = v.y;
  }
}

// ---- two-level grid barrier (validated round 5) ----
__device__ __forceinline__ void gridbar(unsigned* flags, unsigned* release,
                                        unsigned ep, int tid, int blk) {
  __syncthreads();
  if (tid == 0)
    __hip_atomic_store(flags + blk * 16, ep, __ATOMIC_RELAXED, SCOPE_AGENT);
  if (blk == 0) {
    if (tid < NB) {
      while (__hip_atomic_load(flags + tid * 16, __ATOMIC_RELAXED, SCOPE_AGENT) < ep)
        __builtin_amdgcn_s_sleep(1);
    }
    __syncthreads();
    if (tid == 0)
      __hip_atomic_store(release, ep, __ATOMIC_RELAXED, SCOPE_AGENT);
  } else {
    if (tid == 0) {
      while (__hip_atomic_load(release, __ATOMIC_RELAXED, SCOPE_AGENT) < ep)
        __builtin_amdgcn_s_sleep(1);
    }
  }
  __syncthreads();
}

// one row dot-product per wave (f32); x in LDS; K compile-time
template<int K>
__device__ __forceinline__ float rowdotT(const float* __restrict__ row,
                                         const float* __restrict__ x, int ln) {
  constexpr int NFULL = K / 256;
  constexpr int REM   = K - NFULL * 256;
  const int base = ln * 4;
  float4 w[NFULL + (REM ? 1 : 0)];
  #pragma unroll
  for (int i = 0; i < NFULL; ++i)
    w[i] = *reinterpret_cast<const float4*>(row + base + i * 256);
  bool tail = false;
  if constexpr (REM != 0) {
    tail = (base + NFULL * 256 + 3 < K);
    if (tail) w[NFULL] = *reinterpret_cast<const float4*>(row + base + NFULL * 256);
  }
  float acc = 0.f;
  #pragma unroll
  for (int i = 0; i < NFULL; ++i) {
    const float4 xv = *reinterpret_cast<const float4*>(x + base + i * 256);
    acc = fmaf(w[i].x, xv.x, acc);
    acc = fmaf(w[i].y, xv.y, acc);
    acc = fmaf(w[i].z, xv.z, acc);
    acc = fmaf(w[i].w, xv.w, acc);
  }
  if constexpr (REM != 0) {
    if (tail) {
      const float4 xv = *reinterpret_cast<const float4*>(x + base + NFULL * 256);
      acc = fmaf(w[NFULL].x, xv.x, acc);
      acc = fmaf(w[NFULL].y, xv.y, acc);
      acc = fmaf(w[NFULL].z, xv.z, acc);
      acc = fmaf(w[NFULL].w, xv.w, acc);
    }
  }
  #pragma unroll
  for (int off = 32; off; off >>= 1) acc += __shfl_xor(acc, off, 64);
  return acc;
}

// ---- balanced 24-row fp16 block-task sweep ----
// 24 rows x KP halves flattened over 16 waves: each wave covers exactly 3072
// halves (1.5 rows) = 6 x 16B loads per lane. Pair-reduction in LDS.
__device__ __forceinline__ void sweep24(const _Float16* __restrict__ W,
                                        const float* __restrict__ bias,
                                        int row0, int nrows,
                                        const _Float16* __restrict__ xh,
                                        float* __restrict__ outw,
                                        bool relu,
                                        int wv, int ln, int tid, float* red)
{
  const _Float16* wp = W + (size_t)row0 * KP + wv * 3072 + ln * 8;
  uint4 w[6];
  #pragma unroll
  for (int c = 0; c < 6; ++c)
    w[c] = *reinterpret_cast<const uint4*>(wp + c * 512);
  float a0 = 0.f, a1 = 0.f;
  const int first = (3 * wv) >> 1;
  #pragma unroll
  for (int c = 0; c < 6; ++c) {
    const int flat = wv * 3072 + c * 512;
    const int sel  = (flat >> 11) - first;       // 0 or 1, lane-invariant
    const int col  = (flat & (KP - 1)) + ln * 8;
    const uint4 xv = *reinterpret_cast<const uint4*>(xh + col);
    union { uint4 u; h2v h[4]; } wu, xu;
    wu.u = w[c]; xu.u = xv;
    float acc = sel ? a1 : a0;
    #pragma unroll
    for (int q = 0; q < 4; ++q)
      acc = __builtin_amdgcn_fdot2(wu.h[q], xu.h[q], acc, false);
    if (sel) a1 = acc; else a0 = acc;
  }
  #pragma unroll
  for (int off = 32; off; off >>= 1) {
    a0 += __shfl_xor(a0, off, 64);
    a1 += __shfl_xor(a1, off, 64);
  }
  __syncthreads();                 // protect red across back-to-back calls
  if (ln == 0) { red[wv * 2] = a0; red[wv * 2 + 1] = a1; }
  __syncthreads();
  if (tid < nrows) {
    const int k = tid / 3, m = tid % 3;
    float v = (m == 0) ? red[4 * k]
            : (m == 1) ? red[4 * k + 1] + red[4 * k + 2]
                       : red[4 * k + 3];
    v += bias[row0 + tid];
    if (relu) v = fmaxf(v, 0.f);
    st_coh(outw + row0 + tid, v);
  }
}

// ---- f32 -> fp16 padded-layout conversion ----
__global__ __launch_bounds__(256)
void convh(const float* __restrict__ src, _Float16* __restrict__ dst,
           int rows, int K, int padrows) {
  const size_t total = (size_t)padrows * KP;
  for (size_t i = (size_t)blockIdx.x * blockDim.x + threadIdx.x; i < total;
       i += (size_t)gridDim.x * blockDim.x) {
    const int r = (int)(i >> 11), c = (int)(i & (KP - 1));
    float v = (r < rows && c < K) ? src[(size_t)r * K + c] : 0.f;
    dst[i] = (_Float16)v;
  }
}

// ================= fp16 main kernel =================
__global__ __launch_bounds__(NT)
void knet_f16(const float* __restrict__ y, const float* __restrict__ m1x0,
              const float* __restrict__ F, const float* __restrict__ Hm,
              const float* __restrict__ h0,
              const float* __restrict__ W1, const float* __restrict__ b1,
              const float* __restrict__ Wi0, const float* __restrict__ Wh0,
              const float* __restrict__ bi0, const float* __restrict__ bh0,
              const float* __restrict__ Wi1, const float* __restrict__ Wh1,
              const float* __restrict__ bi1, const float* __restrict__ bh1,
              const float* __restrict__ W2, const float* __restrict__ b2,
              const float* __restrict__ W3, const float* __restrict__ b3,
              float* __restrict__ out, float* __restrict__ ws)
{
  const int blk = blockIdx.x, tid = threadIdx.x;
  const int wv = tid >> 6, ln = tid & 63;

  float* a_ws   = ws;            // 1600
  float* gi0_ws = ws + 1600;     // 6000
  float* gh0_ws = ws + 7600;     // 6000
  float* gi1_ws = ws + 13600;    // 6000
  float* gh1_ws = ws + 19600;    // 6000
  float* g_ws   = ws + 25600;    // 400
  unsigned* flags   = (unsigned*)(ws + 26624);
  unsigned* release = flags + NB * 16;

  const _Float16* whbase = (const _Float16*)((const char*)ws + 131072);
  const _Float16* Wi0h = whbase;
  const _Float16* Wh0h = whbase + (size_t)G3 * KP;
  const _Float16* Wi1h = whbase + (size_t)2 * G3 * KP;
  const _Float16* Wh1h = whbase + (size_t)3 * G3 * KP;
  const _Float16* W2h  = whbase + (size_t)4 * G3 * KP;

  __shared__ __align__(16) _Float16 ah[KP];
  __shared__ __align__(16) _Float16 h1h[KP];
  __shared__ __align__(16) _Float16 h2h[KP];
  __shared__ __align__(16) float h1l[HID];
  __shared__ __align__(16) float h2l[HID];
  __shared__ __align__(16) float xs[416];
  __shared__ float red[32];
  __shared__ float post_s[MM], prevpost_s[MM], prevprior_s[MM], prior_s[MM];
  __shared__ float dy_s[NN], yprev_s[NN], tmp_s[MM];
  __shared__ float d1_s[NN], d3_s[MM], d4_s[MM];
  __shared__ float kin_s[32], nrm_s[3];
  __shared__ float v_s[MM * NN], np_s[MM];

  for (int j = tid; j < HID; j += NT) {
    float v1 = h0[j], v2 = h0[HID + j];
    h1l[j] = v1; h2l[j] = v2;
    h1h[j] = (_Float16)v1; h2h[j] = (_Float16)v2;
  }
  for (int j = HID + tid; j < KP; j += NT) { h1h[j] = (_Float16)0.f; h2h[j] = (_Float16)0.f; }
  for (int j = H1 + tid; j < KP; j += NT) ah[j] = (_Float16)0.f;
  __syncthreads();

  unsigned ep = 0;

  for (int t = 0; t < TT; ++t) {
    // ---- P1: Wh1 (250 blk-tasks) + Wh0 tasks 0..4 (+all at t==0); serial on 255 ----
    if (blk == NB - 1) {
      if (t > 0) {
        stage_coh(g_ws, xs, H2, tid);
        __syncthreads();
        for (int r = wv; r < MM * NN; r += NW) {
          float acc = rowdotT<H2>(W3 + (size_t)r * H2, xs, ln);
          if (ln == 0) v_s[r] = acc + b3[r];
        }
        __syncthreads();
        if (tid < MM) {
          float np = prior_s[tid];
          #pragma unroll
          for (int j = 0; j < NN; ++j) np = fmaf(v_s[tid * NN + j], dy_s[j], np);
          out[tid * TT + (t - 1)] = np;
          np_s[tid] = np;
        }
        __syncthreads();
        if (tid < MM) {
          prevpost_s[tid]  = post_s[tid];
          prevprior_s[tid] = prior_s[tid];
          post_s[tid]      = np_s[tid];
        }
        __syncthreads();
      } else {
        if (tid < MM) {
          post_s[tid]      = m1x0[tid];
          prevpost_s[tid]  = 0.f;
          prevprior_s[tid] = m1x0[tid];
          float tv = 0.f;
          for (int j = 0; j < MM; ++j) tv = fmaf(F[tid * MM + j], m1x0[j], tv);
          tmp_s[tid] = tv;
        }
        __syncthreads();
        if (tid < NN) {
          float yp = 0.f;
          for (int j = 0; j < MM; ++j) yp = fmaf(Hm[tid * MM + j], tmp_s[j], yp);
          yprev_s[tid] = yp;
        }
        __syncthreads();
      }
      if (tid < MM) {
        float pr = 0.f;
        for (int j = 0; j < MM; ++j) pr = fmaf(F[tid * MM + j], post_s[j], pr);
        prior_s[tid] = pr;
      }
      __syncthreads();
      if (tid < NN) {
        float my = 0.f;
        for (int j = 0; j < MM; ++j) my = fmaf(Hm[tid * MM + j], prior_s[j], my);
        float yt = y[tid * TT + t];
        dy_s[tid] = yt - my;
        d1_s[tid] = yt - ((t == 0) ? yprev_s[tid] : y[tid * TT + (t - 1)]);
        d3_s[tid] = post_s[tid] - prevpost_s[tid];
        d4_s[tid] = post_s[tid] - prevprior_s[tid];
      }
      __syncthreads();
      if (tid == 0) {
        float n1 = 0.f, n3 = 0.f, n4 = 0.f;
        for (int j = 0; j < NN; ++j) n1 += d1_s[j] * d1_s[j];
        for (int j = 0; j < MM; ++j) { n3 += d3_s[j] * d3_s[j]; n4 += d4_s[j] * d4_s[j]; }
        nrm_s[0] = fmaxf(sqrtf(n1), 1e-12f);
        nrm_s[1] = fmaxf(sqrtf(n3), 1e-12f);
        nrm_s[2] = fmaxf(sqrtf(n4), 1e-12f);
      }
      __syncthreads();
      if (tid < NN) kin_s[tid] = d1_s[tid] / nrm_s[0];
      if (tid < MM) {
        kin_s[NN + tid]      = d3_s[tid] / nrm_s[1];
        kin_s[NN + MM + tid] = d4_s[tid] / nrm_s[2];
      }
      __syncthreads();
      for (int r = tid; r < H1; r += NT) {
        float acc = b1[r];
        const float* row = W1 + (size_t)r * 30;
        #pragma unroll
        for (int k = 0; k < 30; ++k) acc = fmaf(row[k], kin_s[k], acc);
        st_coh(a_ws + r, fmaxf(acc, 0.f));
      }
    } else if (blk < 250) {
      sweep24(Wh1h, bh1, RPB * blk, RPB, h2h, gh1_ws, false, wv, ln, tid, red);
      if (t == 0)
        sweep24(Wh0h, bh0, RPB * blk, RPB, h1h, gh0_ws, false, wv, ln, tid, red);
    } else {
      sweep24(Wh0h, bh0, RPB * (blk - 250), RPB, h1h, gh0_ws, false, wv, ln, tid, red);
    }
    ++ep; gridbar(flags, release, ep, tid, blk);

    // ---- P2: Wi0 (250 tasks) + Wh0 tasks 5..10 ----
    if (blk < 250) {
      const int n2 = H1 >> 1;
      for (int j = tid; j < n2; j += NT) {
        float2 v = ld_coh2(a_ws + 2 * j);
        ah[2 * j]     = (_Float16)v.x;
        ah[2 * j + 1] = (_Float16)v.y;
      }
      __syncthreads();
      sweep24(Wi0h, bi0, RPB * blk, RPB, ah, gi0_ws, false, wv, ln, tid, red);
    } else {
      sweep24(Wh0h, bh0, RPB * (blk - 245), RPB, h1h, gh0_ws, false, wv, ln, tid, red);
    }
    ++ep; gridbar(flags, release, ep, tid, blk);

    // ---- P3: combine1 (all) then Wi1 (250 tasks) ----
    {
      for (int j = tid; j < HID / 2; j += NT) {
        float2 ir = ld_coh2(gi0_ws + 2 * j),            hr = ld_coh2(gh0_ws + 2 * j);
        float2 iz = ld_coh2(gi0_ws + HID + 2 * j),      hz = ld_coh2(gh0_ws + HID + 2 * j);
        float2 in_ = ld_coh2(gi0_ws + 2 * HID + 2 * j), hn = ld_coh2(gh0_ws + 2 * HID + 2 * j);
        float r0 = sigf(ir.x + hr.x), r1 = sigf(ir.y + hr.y);
        float z0 = sigf(iz.x + hz.x), z1 = sigf(iz.y + hz.y);
        float n0 = tanhfast(in_.x + r0 * hn.x), n1 = tanhfast(in_.y + r1 * hn.y);
        float o0 = (1.f - z0) * n0 + z0 * h1l[2 * j];
        float o1 = (1.f - z1) * n1 + z1 * h1l[2 * j + 1];
        h1l[2 * j] = o0; h1l[2 * j + 1] = o1;
        h1h[2 * j] = (_Float16)o0; h1h[2 * j + 1] = (_Float16)o1;
      }
      __syncthreads();
      if (blk < 250)
        sweep24(Wi1h, bi1, RPB * blk, RPB, h1h, gi1_ws, false, wv, ln, tid, red);
    }
    ++ep; gridbar(flags, release, ep, tid, blk);

    // ---- P4: combine2 (all) then Wh0 tasks 11..249 | W2 tasks 0..16 ----
    {
      for (int j = tid; j < HID / 2; j += NT) {
        float2 ir = ld_coh2(gi1_ws + 2 * j),            hr = ld_coh2(gh1_ws + 2 * j);
        float2 iz = ld_coh2(gi1_ws + HID + 2 * j),      hz = ld_coh2(gh1_ws + HID + 2 * j);
        float2 in_ = ld_coh2(gi1_ws + 2 * HID + 2 * j), hn = ld_coh2(gh1_ws + 2 * HID + 2 * j);
        float r0 = sigf(ir.x + hr.x), r1 = sigf(ir.y + hr.y);
        float z0 = sigf(iz.x + hz.x), z1 = sigf(iz.y + hz.y);
        float n0 = tanhfast(in_.x + r0 * hn.x), n1 = tanhfast(in_.y + r1 * hn.y);
        float o0 = (1.f - z0) * n0 + z0 * h2l[2 * j];
        float o1 = (1.f - z1) * n1 + z1 * h2l[2 * j + 1];
        h2l[2 * j] = o0; h2l[2 * j + 1] = o1;
        h2h[2 * j] = (_Float16)o0; h2h[2 * j + 1] = (_Float16)o1;
      }
      __syncthreads();
      if (blk < 239) {
        sweep24(Wh0h, bh0, RPB * (blk + 11), RPB, h1h, gh0_ws, false, wv, ln, tid, red);
      } else {
        const int task = blk - 239;                 // 0..16
        const int row0 = RPB * task;
        const int nr = (H2 - row0 < RPB) ? (H2 - row0) : RPB;
        sweep24(W2h, b2, row0, nr, h2h, g_ws, true, wv, ln, tid, red);
      }
    }
    ++ep; gridbar(flags, release, ep, tid, blk);
  }

  // ---- tail: finalize step T-1 ----
  if (blk == NB - 1) {
    stage_coh(g_ws, xs, H2, tid);
    __syncthreads();
    for (int r = wv; r < MM * NN; r += NW) {
      float acc = rowdotT<H2>(W3 + (size_t)r * H2, xs, ln);
      if (ln == 0) v_s[r] = acc + b3[r];
    }
    __syncthreads();
    if (tid < MM) {
      float np = prior_s[tid];
      #pragma unroll
      for (int j = 0; j < NN; ++j) np = fmaf(v_s[tid * NN + j], dy_s[j], np);
      out[tid * TT + (TT - 1)] = np;
    }
  }
}

// ================= f32 fallback (round-5 kernel, proven) =================
__global__ __launch_bounds__(NT)
void knet_f32(const float* __restrict__ y, const float* __restrict__ m1x0,
              const float* __restrict__ F, const float* __restrict__ Hm,
              const float* __restrict__ h0,
              const float* __restrict__ W1, const float* __restrict__ b1,
              const float* __restrict__ Wi0, const float* __restrict__ Wh0,
              const float* __restrict__ bi0, const float* __restrict__ bh0,
              const float* __restrict__ Wi1, const float* __restrict__ Wh1,
              const float* __restrict__ bi1, const float* __restrict__ bh1,
              const float* __restrict__ W2, const float* __restrict__ b2,
              const float* __restrict__ W3, const float* __restrict__ b3,
              float* __restrict__ out, float* __restrict__ ws)
{
  const int blk = blockIdx.x, tid = threadIdx.x;
  const int wv = tid >> 6, ln = tid & 63;

  float* a_ws   = ws;
  float* gi0_ws = ws + 1600;
  float* gh0_ws = ws + 7600;
  float* gi1_ws = ws + 13600;
  float* gh1_ws = ws + 19600;
  float* g_ws   = ws + 25600;
  unsigned* flags   = (unsigned*)(ws + 26624);
  unsigned* release = flags + NB * 16;

  __shared__ __align__(16) float xs[1664];
  __shared__ __align__(16) float h1l[HID];
  __shared__ __align__(16) float h2l[HID];
  __shared__ float post_s[MM], prevpost_s[MM], prevprior_s[MM], prior_s[MM];
  __shared__ float dy_s[NN], yprev_s[NN], tmp_s[MM];
  __shared__ float d1_s[NN], d3_s[MM], d4_s[MM];
  __shared__ float kin_s[32], nrm_s[3];
  __shared__ float v_s[MM * NN], np_s[MM];

  for (int j = tid; j < HID; j += NT) { h1l[j] = h0[j]; h2l[j] = h0[HID + j]; }
  __syncthreads();

  unsigned ep = 0;

  for (int t = 0; t < TT; ++t) {
    if (blk == NB - 1) {
      if (t > 0) {
        stage_coh(g_ws, xs, H2, tid);
        __syncthreads();
        for (int r = wv; r < MM * NN; r += NW) {
          float acc = rowdotT<H2>(W3 + (size_t)r * H2, xs, ln);
          if (ln == 0) v_s[r] = acc + b3[r];
        }
        __syncthreads();
        if (tid < MM) {
          float np = prior_s[tid];
          #pragma unroll
          for (int j = 0; j < NN; ++j) np = fmaf(v_s[tid * NN + j], dy_s[j], np);
          out[tid * TT + (t - 1)] = np;
          np_s[tid] = np;
        }
        __syncthreads();
        if (tid < MM) {
          prevpost_s[tid]  = post_s[tid];
          prevprior_s[tid] = prior_s[tid];
          post_s[tid]      = np_s[tid];
        }
        __syncthreads();
      } else {
        if (tid < MM) {
          post_s[tid]      = m1x0[tid];
          prevpost_s[tid]  = 0.f;
          prevprior_s[tid] = m1x0[tid];
          float tv = 0.f;
          for (int j = 0; j < MM; ++j) tv = fmaf(F[tid * MM + j], m1x0[j], tv);
          tmp_s[tid] = tv;
        }
        __syncthreads();
        if (tid < NN) {
          float yp = 0.f;
          for (int j = 0; j < MM; ++j) yp = fmaf(Hm[tid * MM + j], tmp_s[j], yp);
          yprev_s[tid] = yp;
        }
        __syncthreads();
      }
      if (tid < MM) {
        float pr = 0.f;
        for (int j = 0; j < MM; ++j) pr = fmaf(F[tid * MM + j], post_s[j], pr);
        prior_s[tid] = pr;
      }
      __syncthreads();
      if (tid < NN) {
        float my = 0.f;
        for (int j = 0; j < MM; ++j) my = fmaf(Hm[tid * MM + j], prior_s[j], my);
        float yt = y[tid * TT + t];
        dy_s[tid] = yt - my;
        d1_s[tid] = yt - ((t == 0) ? yprev_s[tid] : y[tid * TT + (t - 1)]);
        d3_s[tid] = post_s[tid] - prevpost_s[tid];
        d4_s[tid] = post_s[tid] - prevprior_s[tid];
      }
      __syncthreads();
      if (tid == 0) {
        float n1 = 0.f, n3 = 0.f, n4 = 0.f;
        for (int j = 0; j < NN; ++j) n1 += d1_s[j] * d1_s[j];
        for (int j = 0; j < MM; ++j) { n3 += d3_s[j] * d3_s[j]; n4 += d4_s[j] * d4_s[j]; }
        nrm_s[0] = fmaxf(sqrtf(n1), 1e-12f);
        nrm_s[1] = fmaxf(sqrtf(n3), 1e-12f);
        nrm_s[2] = fmaxf(sqrtf(n4), 1e-12f);
      }
      __syncthreads();
      if (tid < NN) kin_s[tid] = d1_s[tid] / nrm_s[0];
      if (tid < MM) {
        kin_s[NN + tid]      = d3_s[tid] / nrm_s[1];
        kin_s[NN + MM + tid] = d4_s[tid] / nrm_s[2];
      }
      __syncthreads();
      for (int r = tid; r < H1; r += NT) {
        float acc = b1[r];
        const float* row = W1 + (size_t)r * 30;
        #pragma unroll
        for (int k = 0; k < 30; ++k) acc = fmaf(row[k], kin_s[k], acc);
        st_coh(a_ws + r, fmaxf(acc, 0.f));
      }
    } else {
      const int gw = blk * NW + wv;
      for (int r = gw; r < G3; r += (NB - 1) * NW) {
        float acc = rowdotT<HID>(Wh1 + (size_t)r * HID, h2l, ln);
        if (ln == 0) st_coh(gh1_ws + r, acc + bh1[r]);
      }
      if (t == 0) {
        for (int r = gw; r < G3; r += (NB - 1) * NW) {
          float acc = rowdotT<HID>(Wh0 + (size_t)r * HID, h1l, ln);
          if (ln == 0) st_coh(gh0_ws + r, acc + bh0[r]);
        }
      }
    }
    ++ep; gridbar(flags, release, ep, tid, blk);

    stage_coh(a_ws, xs, H1, tid);
    __syncthreads();
    {
      const int gw = blk * NW + wv;
      for (int r = gw; r < G3; r += NB * NW) {
        float acc = rowdotT<H1>(Wi0 + (size_t)r * H1, xs, ln);
        if (ln == 0) st_coh(gi0_ws + r, acc + bi0[r]);
      }
    }
    ++ep; gridbar(flags, release, ep, tid, blk);

    {
      for (int j = tid; j < HID / 2; j += NT) {
        float2 ir = ld_coh2(gi0_ws + 2 * j),            hr = ld_coh2(gh0_ws + 2 * j);
        float2 iz = ld_coh2(gi0_ws + HID + 2 * j),      hz = ld_coh2(gh0_ws + HID + 2 * j);
        float2 in_ = ld_coh2(gi0_ws + 2 * HID + 2 * j), hn = ld_coh2(gh0_ws + 2 * HID + 2 * j);
        float r0 = sigf(ir.x + hr.x), r1 = sigf(ir.y + hr.y);
        float z0 = sigf(iz.x + hz.x), z1 = sigf(iz.y + hz.y);
        float n0 = tanhfast(in_.x + r0 * hn.x), n1 = tanhfast(in_.y + r1 * hn.y);
        h1l[2 * j]     = (1.f - z0) * n0 + z0 * h1l[2 * j];
        h1l[2 * j + 1] = (1.f - z1) * n1 + z1 * h1l[2 * j + 1];
      }
      __syncthreads();
      const int gw = blk * NW + wv;
      for (int r = gw; r < G3; r += NB * NW) {
        float acc = rowdotT<HID>(Wi1 + (size_t)r * HID, h1l, ln);
        if (ln == 0) st_coh(gi1_ws + r, acc + bi1[r]);
      }
    }
    ++ep; gridbar(flags, release, ep, tid, blk);

    {
      for (int j = tid; j < HID / 2; j += NT) {
        float2 ir = ld_coh2(gi1_ws + 2 * j),            hr = ld_coh2(gh1_ws + 2 * j);
        float2 iz = ld_coh2(gi1_ws + HID + 2 * j),      hz = ld_coh2(gh1_ws + HID + 2 * j);
        float2 in_ = ld_coh2(gi1_ws + 2 * HID + 2 * j), hn = ld_coh2(gh1_ws + 2 * HID + 2 * j);
        float r0 = sigf(ir.x + hr.x), r1 = sigf(ir.y + hr.y);
        float z0 = sigf(iz.x + hz.x), z1 = sigf(iz.y + hz.y);
        float n0 = tanhfast(in_.x + r0 * hn.x), n1 = tanhfast(in_.y + r1 * hn.y);
        h2l[2 * j]     = (1.f - z0) * n0 + z0 * h2l[2 * j];
        h2l[2 * j + 1] = (1.f - z1) * n1 + z1 * h2l[2 * j + 1];
      }
      __syncthreads();
      const int gw = blk * NW + wv;
      for (int r = gw; r < H2 + G3; r += NB * NW) {
        if (r < H2) {
          float acc = rowdotT<HID>(W2 + (size_t)r * HID, h2l, ln);
          if (ln == 0) st_coh(g_ws + r, fmaxf(acc + b2[r], 0.f));
        } else {
          const int rr = r - H2;
          float acc = rowdotT<HID>(Wh0 + (size_t)rr * HID, h1l, ln);
          if (ln == 0) st_coh(gh0_ws + rr, acc + bh0[rr]);
        }
      }
    }
    ++ep; gridbar(flags, release, ep, tid, blk);
  }

  if (blk == NB - 1) {
    stage_coh(g_ws, xs, H2, tid);
    __syncthreads();
    for (int r = wv; r < MM * NN; r += NW) {
      float acc = rowdotT<H2>(W3 + (size_t)r * H2, xs, ln);
      if (ln == 0) v_s[r] = acc + b3[r];
    }
    __syncthreads();
    if (tid < MM) {
      float np = prior_s[tid];
      #pragma unroll
      for (int j = 0; j < NN; ++j) np = fmaf(v_s[tid * NN + j], dy_s[j], np);
      out[tid * TT + (TT - 1)] = np;
    }
  }
}

extern "C" void kernel_launch(void* const* d_in, const int* in_sizes, int n_in,
                              void* d_out, int out_size, void* d_ws, size_t ws_size,
                              hipStream_t stream) {
  const float* y    = (const float*)d_in[0];
  const float* m1x0 = (const float*)d_in[1];
  const float* F    = (const float*)d_in[2];
  const float* Hm   = (const float*)d_in[3];
  const float* h0   = (const float*)d_in[4];
  const float* W1   = (const float*)d_in[5];
  const float* b1   = (const float*)d_in[6];
  const float* Wi0  = (const float*)d_in[7];
  const float* Wh0  = (const float*)d_in[8];
  const float* bi0  = (const float*)d_in[9];
  const float* bh0  = (const float*)d_in[10];
  const float* Wi1  = (const float*)d_in[11];
  const float* Wh1  = (const float*)d_in[12];
  const float* bi1  = (const float*)d_in[13];
  const float* bh1  = (const float*)d_in[14];
  const float* W2   = (const float*)d_in[15];
  const float* b2   = (const float*)d_in[16];
  const float* W3   = (const float*)d_in[17];
  const float* b3   = (const float*)d_in[18];
  float* out = (float*)d_out;
  float* ws  = (float*)d_ws;

  const size_t NEED = 131072 + ((size_t)4 * G3 * KP + 408 * KP) * 2;

  // zero barrier flags + release (epochs restart at 1 each launch)
  hipMemsetAsync((char*)d_ws + 26624 * sizeof(float), 0, NB * 64 + 64, stream);

  void* args[] = { &y, &m1x0, &F, &Hm, &h0, &W1, &b1, &Wi0, &Wh0, &bi0, &bh0,
                   &Wi1, &Wh1, &bi1, &bh1, &W2, &b2, &W3, &b3, &out, &ws };

  if (ws_size >= NEED) {
    _Float16* wh = (_Float16*)((char*)d_ws + 131072);
    convh<<<2048, 256, 0, stream>>>(Wi0, wh,                         G3, H1,  G3);
    convh<<<2048, 256, 0, stream>>>(Wh0, wh + (size_t)G3 * KP,       G3, HID, G3);
    convh<<<2048, 256, 0, stream>>>(Wi1, wh + (size_t)2 * G3 * KP,   G3, HID, G3);
    convh<<<2048, 256, 0, stream>>>(Wh1, wh + (size_t)3 * G3 * KP,   G3, HID, G3);
    convh<<<2048, 256, 0, stream>>>(W2,  wh + (size_t)4 * G3 * KP,   H2, HID, 408);
    hipLaunchCooperativeKernel((const void*)knet_f16, dim3(NB), dim3(NT),
                               args, 0, stream);
  } else {
    hipLaunchCooperativeKernel((const void*)knet_f32, dim3(NB), dim3(NT),
                               args, 0, stream);
  }
}